// Round 1
// baseline (164.323 us; speedup 1.0000x reference)
//
#include <hip/hip_runtime.h>

// BQWarp: ball query, N=32768 queries vs G=4096 db points, radius 0.25, K=10.
// Outputs (concatenated in d_out, float32):
//   [0, N*K)          mapping  (first-K in-radius db indices, 0 if invalid), as floats
//   [N*K, N*K*4)      coords   (N,K,3) gathered db coords, 0 if invalid
//
// Strategy: db (48 KB) staged in LDS; one thread per query scans db in index
// order (wave-uniform loop -> broadcast ds_read). Wave-wide early exit when
// all 64 lanes have found K neighbors. Distance computed with __f*_rn
// intrinsics to forbid FMA contraction and bit-match the numpy reference:
//   d2 = ((dx*dx + dy*dy) + dz*dz), each op separately rounded.

#define BQ_K 10
#define BQ_R2 0.0625f   // 0.25^2, exactly representable

__global__ __launch_bounds__(64, 1) void bqwarp_kernel(
    const float* __restrict__ x,     // N*3 query coords
    const float* __restrict__ db,    // G*3 database coords
    float* __restrict__ out_map,     // N*K
    float* __restrict__ out_pts,     // N*K*3
    int N, int G)
{
    __shared__ float lds[3 * 4096];  // 48 KB

    const int tid = threadIdx.x;

    // Stage database into LDS (coalesced-ish; tiny: 48 KB per block).
    for (int i = tid; i < 3 * G; i += 64) {
        lds[i] = db[i];
    }
    __syncthreads();

    const int q = blockIdx.x * 64 + tid;
    if (q >= N) return;

    const float qx = x[3 * q + 0];
    const float qy = x[3 * q + 1];
    const float qz = x[3 * q + 2];

    float* __restrict__ omap = out_map + (size_t)q * BQ_K;
    float* __restrict__ opts = out_pts + (size_t)q * BQ_K * 3;

    int cnt = 0;

    for (int g = 0; g < G; g += 4) {
#pragma unroll
        for (int u = 0; u < 4; ++u) {
            const int gi = g + u;
            const float px = lds[3 * gi + 0];
            const float py = lds[3 * gi + 1];
            const float pz = lds[3 * gi + 2];
            // Exact numpy rounding order; no FMA contraction.
            const float dx = __fsub_rn(qx, px);
            const float dy = __fsub_rn(qy, py);
            const float dz = __fsub_rn(qz, pz);
            const float d2 = __fadd_rn(
                __fadd_rn(__fmul_rn(dx, dx), __fmul_rn(dy, dy)),
                __fmul_rn(dz, dz));
            if (d2 <= BQ_R2) {
                if (cnt < BQ_K) {
                    omap[cnt] = (float)gi;
                    opts[3 * cnt + 0] = px;
                    opts[3 * cnt + 1] = py;
                    opts[3 * cnt + 2] = pz;
                    ++cnt;
                }
            }
        }
        // Wave-wide early exit: all 64 lanes found K neighbors.
        if (__all(cnt >= BQ_K)) break;
    }

    // Zero-fill remaining slots (harness poisons d_out with 0xAA).
    for (int k = cnt; k < BQ_K; ++k) {
        omap[k] = 0.0f;
        opts[3 * k + 0] = 0.0f;
        opts[3 * k + 1] = 0.0f;
        opts[3 * k + 2] = 0.0f;
    }
}

extern "C" void kernel_launch(void* const* d_in, const int* in_sizes, int n_in,
                              void* d_out, int out_size, void* d_ws, size_t ws_size,
                              hipStream_t stream) {
    const float* x  = (const float*)d_in[0];   // (1, 32768, 3) float32
    const float* pg = (const float*)d_in[1];   // (1, 32, 16, 8, 3) float32

    const int N = in_sizes[0] / 3;   // 32768
    const int G = in_sizes[1] / 3;   // 4096

    float* out_map = (float*)d_out;                    // N*K floats
    float* out_pts = out_map + (size_t)N * BQ_K;       // N*K*3 floats

    const int block = 64;
    const int nblk = (N + block - 1) / block;
    bqwarp_kernel<<<nblk, block, 0, stream>>>(x, pg, out_map, out_pts, N, G);
}

// Round 2
// 68.400 us; speedup vs baseline: 2.4024x; 2.4024x over previous
//
#include <hip/hip_runtime.h>

// BQWarp: ball query, N=32768 queries vs G=4096 db points, radius 0.25, K=10.
// Outputs (concatenated in d_out, float32):
//   [0, N*K)       mapping (first-K in-radius db indices in index order, 0 if invalid)
//   [N*K, N*K*4)   coords  (N,K,3) gathered db coords, 0 if invalid
//
// Round 2: wave-per-query ballot scan.
//   - 64 lanes check 64 consecutive db points per iteration.
//   - __ballot -> 64-bit hit mask; lane's output slot = cnt + popc(mask below lane).
//   - Early exit per query when cnt >= K (uniform branch, cnt derived from ballot).
//   - db read directly from global (48 KB, L2-resident); no LDS.
//   - __f*_rn intrinsics pin the exact numpy rounding order (no FMA contraction)
//     so the d2 <= R^2 mask is bit-identical to the reference.

#define BQ_K 10
#define BQ_R2 0.0625f   // 0.25^2 exactly representable

__global__ __launch_bounds__(256) void bqwarp_ballot_kernel(
    const float* __restrict__ x,     // N*3 query coords
    const float* __restrict__ db,    // G*3 database coords
    float* __restrict__ out_map,     // N*K (indices as floats)
    float* __restrict__ out_pts,     // N*K*3
    int N, int G)
{
    const int lane = threadIdx.x & 63;
    const int wave = threadIdx.x >> 6;
    const int q = blockIdx.x * 4 + wave;   // one query per wave
    if (q >= N) return;                    // wave-uniform

    const float qx = x[3 * q + 0];
    const float qy = x[3 * q + 1];
    const float qz = x[3 * q + 2];

    float* __restrict__ omap = out_map + (size_t)q * BQ_K;
    float* __restrict__ opts = out_pts + (size_t)q * BQ_K * 3;

    const unsigned long long below = (1ull << lane) - 1ull;

    int cnt = 0;                            // uniform across the wave
    const int nchunk = (G + 63) >> 6;

    for (int c = 0; c < nchunk; ++c) {
        const int gi = (c << 6) | lane;
        const int gil = gi < G ? gi : G - 1;           // clamp (G=4096: no-op)
        const float px = db[3 * gil + 0];
        const float py = db[3 * gil + 1];
        const float pz = db[3 * gil + 2];
        // Exact numpy rounding order; no FMA contraction.
        const float dx = __fsub_rn(qx, px);
        const float dy = __fsub_rn(qy, py);
        const float dz = __fsub_rn(qz, pz);
        const float d2 = __fadd_rn(
            __fadd_rn(__fmul_rn(dx, dx), __fmul_rn(dy, dy)),
            __fmul_rn(dz, dz));
        const bool hit = (gi < G) && (d2 <= BQ_R2);

        const unsigned long long m = __ballot(hit);
        if (hit) {
            const int slot = cnt + __popcll(m & below);
            if (slot < BQ_K) {
                omap[slot] = (float)gi;
                opts[3 * slot + 0] = px;
                opts[3 * slot + 1] = py;
                opts[3 * slot + 2] = pz;
            }
        }
        cnt += __popcll(m);
        if (cnt >= BQ_K) break;             // uniform
    }

    // Zero-fill unused slots in parallel (d_out is poisoned before each launch).
    const int c0 = cnt < BQ_K ? cnt : BQ_K;
    if (lane >= c0 && lane < BQ_K) {
        omap[lane] = 0.0f;
        opts[3 * lane + 0] = 0.0f;
        opts[3 * lane + 1] = 0.0f;
        opts[3 * lane + 2] = 0.0f;
    }
}

extern "C" void kernel_launch(void* const* d_in, const int* in_sizes, int n_in,
                              void* d_out, int out_size, void* d_ws, size_t ws_size,
                              hipStream_t stream) {
    const float* x  = (const float*)d_in[0];   // (1, 32768, 3) float32
    const float* pg = (const float*)d_in[1];   // (1, 32, 16, 8, 3) float32

    const int N = in_sizes[0] / 3;   // 32768
    const int G = in_sizes[1] / 3;   // 4096

    float* out_map = (float*)d_out;                 // N*K floats
    float* out_pts = out_map + (size_t)N * BQ_K;    // N*K*3 floats

    const int block = 256;                          // 4 waves = 4 queries/block
    const int nblk = (N + 3) / 4;                   // 8192 blocks
    bqwarp_ballot_kernel<<<nblk, block, 0, stream>>>(x, pg, out_map, out_pts, N, G);
}